// Round 2
// baseline (277.597 us; speedup 1.0000x reference)
//
#include <hip/hip_runtime.h>

#define IN_DIM 8192
#define OUT_DIM 8192
#define NROWS 4096
#define THREADS 512
#define JITERS (OUT_DIM / (THREADS * 4))  // 4

// GATE_COEF[16][4] from the reference.
__device__ __constant__ float GATE_COEF[16][4] = {
    {0.f, 0.f, 0.f, 0.f}, {0.f, 0.f, 0.f, 1.f}, {0.f, 1.f, 0.f, -1.f}, {0.f, 1.f, 0.f, 0.f},
    {0.f, 0.f, 1.f, -1.f}, {0.f, 0.f, 1.f, 0.f}, {0.f, 1.f, 1.f, -2.f}, {0.f, 1.f, 1.f, -1.f},
    {1.f, -1.f, -1.f, 1.f}, {1.f, -1.f, -1.f, 2.f}, {1.f, 0.f, -1.f, 0.f}, {1.f, 0.f, -1.f, 1.f},
    {1.f, -1.f, 0.f, 0.f}, {1.f, -1.f, 0.f, 1.f}, {1.f, 0.f, 0.f, -1.f}, {1.f, 0.f, 0.f, 0.f}};

// Kernel A: c[j] = softmax(weights[j,:]) @ GATE_COEF  -> float4 per j
__global__ __launch_bounds__(256) void compute_c_kernel(const float* __restrict__ w,
                                                        float4* __restrict__ c) {
    int j = blockIdx.x * blockDim.x + threadIdx.x;
    if (j >= OUT_DIM) return;
    const float4* wv = (const float4*)(w + (size_t)j * 16);
    float4 w0 = wv[0], w1 = wv[1], w2 = wv[2], w3 = wv[3];
    float wa[16] = {w0.x, w0.y, w0.z, w0.w, w1.x, w1.y, w1.z, w1.w,
                    w2.x, w2.y, w2.z, w2.w, w3.x, w3.y, w3.z, w3.w};
    float m = wa[0];
#pragma unroll
    for (int k = 1; k < 16; ++k) m = fmaxf(m, wa[k]);
    float p[16];
    float s = 0.f;
#pragma unroll
    for (int k = 0; k < 16; ++k) {
        p[k] = __expf(wa[k] - m);
        s += p[k];
    }
    float inv = 1.f / s;
    float c0 = 0.f, c1 = 0.f, c2 = 0.f, c3 = 0.f;
#pragma unroll
    for (int k = 0; k < 16; ++k) {
        c0 = fmaf(p[k], GATE_COEF[k][0], c0);
        c1 = fmaf(p[k], GATE_COEF[k][1], c1);
        c2 = fmaf(p[k], GATE_COEF[k][2], c2);
        c3 = fmaf(p[k], GATE_COEF[k][3], c3);
    }
    c[j] = make_float4(c0 * inv, c1 * inv, c2 * inv, c3 * inv);
}

// Kernel B: one block per row. 512 threads (8 waves), LDS 32 KB -> 4 blocks/CU
// = 32 waves/CU (100% occupancy). Gather loop software-pipelined 1 deep on idx.
__global__ __launch_bounds__(THREADS, 8) void gate_kernel(const float* __restrict__ x,
                                                          const float4* __restrict__ c,
                                                          const int* __restrict__ idx0,
                                                          const int* __restrict__ idx1,
                                                          float* __restrict__ out) {
    __shared__ float row[IN_DIM];
    const int i = blockIdx.x;
    const int tid = threadIdx.x;
    const float4* xr = (const float4*)(x + (size_t)i * IN_DIM);
    float4* rowv = (float4*)row;

    // Stage the 32 KB row: 4 float4 per thread, coalesced.
    float4 s0 = xr[tid];
    float4 s1 = xr[tid + THREADS];
    float4 s2 = xr[tid + 2 * THREADS];
    float4 s3 = xr[tid + 3 * THREADS];

    // Prefetch iteration-0 idx while the stage loads are in flight; their L2
    // latency hides under the staging + barrier.
    const int j0 = tid * 4;
    int4 pi0 = *(const int4*)(idx0 + j0);
    int4 pi1 = *(const int4*)(idx1 + j0);

    rowv[tid] = s0;
    rowv[tid + THREADS] = s1;
    rowv[tid + 2 * THREADS] = s2;
    rowv[tid + 3 * THREADS] = s3;
    __syncthreads();

    float* orow = out + (size_t)i * OUT_DIM;
#pragma unroll
    for (int k = 0; k < JITERS; ++k) {
        const int j = k * (THREADS * 4) + tid * 4;
        const int4 i0 = pi0;
        const int4 i1 = pi1;
        // Issue next iteration's idx loads before this iteration's LDS gathers
        // so the L2 latency overlaps the ds_read chain.
        if (k < JITERS - 1) {
            const int jn = j + THREADS * 4;
            pi0 = *(const int4*)(idx0 + jn);
            pi1 = *(const int4*)(idx1 + jn);
        }
        // c loads: latency hides under the 8 LDS reads below.
        const float4 ca = c[j + 0];
        const float4 cb = c[j + 1];
        const float4 cc = c[j + 2];
        const float4 cd = c[j + 3];
        float a, b;
        float4 o;
        a = row[i0.x]; b = row[i1.x];
        o.x = fmaf(a * b, ca.w, fmaf(b, ca.z, fmaf(a, ca.y, ca.x)));
        a = row[i0.y]; b = row[i1.y];
        o.y = fmaf(a * b, cb.w, fmaf(b, cb.z, fmaf(a, cb.y, cb.x)));
        a = row[i0.z]; b = row[i1.z];
        o.z = fmaf(a * b, cc.w, fmaf(b, cc.z, fmaf(a, cc.y, cc.x)));
        a = row[i0.w]; b = row[i1.w];
        o.w = fmaf(a * b, cd.w, fmaf(b, cd.z, fmaf(a, cd.y, cd.x)));
        *(float4*)(orow + j) = o;
    }
}

extern "C" void kernel_launch(void* const* d_in, const int* in_sizes, int n_in,
                              void* d_out, int out_size, void* d_ws, size_t ws_size,
                              hipStream_t stream) {
    const float* x = (const float*)d_in[0];
    const float* weights = (const float*)d_in[1];
    const int* idx0 = (const int*)d_in[2];
    const int* idx1 = (const int*)d_in[3];
    float* out = (float*)d_out;
    float4* c = (float4*)d_ws;  // OUT_DIM float4s = 128 KB scratch

    compute_c_kernel<<<OUT_DIM / 256, 256, 0, stream>>>(weights, c);
    gate_kernel<<<NROWS, THREADS, 0, stream>>>(x, c, idx0, idx1, out);
}

// Round 3
// 234.788 us; speedup vs baseline: 1.1823x; 1.1823x over previous
//
#include <hip/hip_runtime.h>

#define IN_DIM 8192
#define OUT_DIM 8192
#define NROWS 4096
#define THREADS 512
#define RPB 2                                    // rows per block
#define JITERS (OUT_DIM / (THREADS * 4))         // 4

typedef float v4f __attribute__((ext_vector_type(4)));

// GATE_COEF[16][4] from the reference.
__device__ __constant__ float GATE_COEF[16][4] = {
    {0.f, 0.f, 0.f, 0.f}, {0.f, 0.f, 0.f, 1.f}, {0.f, 1.f, 0.f, -1.f}, {0.f, 1.f, 0.f, 0.f},
    {0.f, 0.f, 1.f, -1.f}, {0.f, 0.f, 1.f, 0.f}, {0.f, 1.f, 1.f, -2.f}, {0.f, 1.f, 1.f, -1.f},
    {1.f, -1.f, -1.f, 1.f}, {1.f, -1.f, -1.f, 2.f}, {1.f, 0.f, -1.f, 0.f}, {1.f, 0.f, -1.f, 1.f},
    {1.f, -1.f, 0.f, 0.f}, {1.f, -1.f, 0.f, 1.f}, {1.f, 0.f, 0.f, -1.f}, {1.f, 0.f, 0.f, 0.f}};

// Kernel A: c[j] = softmax(weights[j,:]) @ GATE_COEF, stored SoA:
// plane p holds cp[j] (OUT_DIM floats each) so gate_kernel's loads coalesce.
__global__ __launch_bounds__(256) void compute_c_kernel(const float* __restrict__ w,
                                                        float* __restrict__ cp) {
    int j = blockIdx.x * blockDim.x + threadIdx.x;
    if (j >= OUT_DIM) return;
    const float4* wv = (const float4*)(w + (size_t)j * 16);
    float4 w0 = wv[0], w1 = wv[1], w2 = wv[2], w3 = wv[3];
    float wa[16] = {w0.x, w0.y, w0.z, w0.w, w1.x, w1.y, w1.z, w1.w,
                    w2.x, w2.y, w2.z, w2.w, w3.x, w3.y, w3.z, w3.w};
    float m = wa[0];
#pragma unroll
    for (int k = 1; k < 16; ++k) m = fmaxf(m, wa[k]);
    float p[16];
    float s = 0.f;
#pragma unroll
    for (int k = 0; k < 16; ++k) {
        p[k] = __expf(wa[k] - m);
        s += p[k];
    }
    float inv = 1.f / s;
    float c0 = 0.f, c1 = 0.f, c2 = 0.f, c3 = 0.f;
#pragma unroll
    for (int k = 0; k < 16; ++k) {
        c0 = fmaf(p[k], GATE_COEF[k][0], c0);
        c1 = fmaf(p[k], GATE_COEF[k][1], c1);
        c2 = fmaf(p[k], GATE_COEF[k][2], c2);
        c3 = fmaf(p[k], GATE_COEF[k][3], c3);
    }
    cp[j] = c0 * inv;
    cp[j + OUT_DIM] = c1 * inv;
    cp[j + 2 * OUT_DIM] = c2 * inv;
    cp[j + 3 * OUT_DIM] = c3 * inv;
}

// Kernel B: 2 rows per block. 64 KB LDS, 512 threads -> 2 blocks/CU (50% occ),
// <=128 VGPRs for deep MLP. idx/c loaded once per 2 rows (12 B metadata/elem).
__global__ __launch_bounds__(THREADS, 4) void gate_kernel(const float* __restrict__ x,
                                                          const float* __restrict__ cp,
                                                          const int* __restrict__ idx0,
                                                          const int* __restrict__ idx1,
                                                          float* __restrict__ out) {
    __shared__ float rows[RPB * IN_DIM];  // 64 KB
    const int r0 = blockIdx.x * RPB;
    const int tid = threadIdx.x;

    // Stage both rows, coalesced, nontemporal (x rows are single-use here).
    const v4f* xr0 = (const v4f*)(x + (size_t)r0 * IN_DIM);
    const v4f* xr1 = (const v4f*)(x + (size_t)(r0 + 1) * IN_DIM);
    v4f* rv0 = (v4f*)rows;
    v4f* rv1 = (v4f*)(rows + IN_DIM);
    v4f st[8];
#pragma unroll
    for (int t = 0; t < 4; ++t) st[t] = __builtin_nontemporal_load(xr0 + tid + t * THREADS);
#pragma unroll
    for (int t = 0; t < 4; ++t) st[4 + t] = __builtin_nontemporal_load(xr1 + tid + t * THREADS);

    // Prefetch iteration-0 idx under the staging latency.
    const int j0 = tid * 4;
    int4 pi0 = *(const int4*)(idx0 + j0);
    int4 pi1 = *(const int4*)(idx1 + j0);

#pragma unroll
    for (int t = 0; t < 4; ++t) rv0[tid + t * THREADS] = st[t];
#pragma unroll
    for (int t = 0; t < 4; ++t) rv1[tid + t * THREADS] = st[4 + t];
    __syncthreads();

    const float* __restrict__ c0p = cp;
    const float* __restrict__ c1p = cp + OUT_DIM;
    const float* __restrict__ c2p = cp + 2 * OUT_DIM;
    const float* __restrict__ c3p = cp + 3 * OUT_DIM;
    float* o0 = out + (size_t)r0 * OUT_DIM;
    float* o1 = out + (size_t)(r0 + 1) * OUT_DIM;

#pragma unroll
    for (int k = 0; k < JITERS; ++k) {
        const int j = k * (THREADS * 4) + tid * 4;
        const int4 i0 = pi0;
        const int4 i1 = pi1;
        if (k < JITERS - 1) {
            const int jn = j + THREADS * 4;
            pi0 = *(const int4*)(idx0 + jn);
            pi1 = *(const int4*)(idx1 + jn);
        }
        // Coalesced SoA c loads: each wave instr reads 1 KB contiguous.
        const v4f c0v = *(const v4f*)(c0p + j);
        const v4f c1v = *(const v4f*)(c1p + j);
        const v4f c2v = *(const v4f*)(c2p + j);
        const v4f c3v = *(const v4f*)(c3p + j);
        // Gathers for both rows issued together (16 independent ds_reads).
        v4f a0, b0, a1, b1;
        a0.x = rows[i0.x]; a0.y = rows[i0.y]; a0.z = rows[i0.z]; a0.w = rows[i0.w];
        b0.x = rows[i1.x]; b0.y = rows[i1.y]; b0.z = rows[i1.z]; b0.w = rows[i1.w];
        a1.x = rows[IN_DIM + i0.x]; a1.y = rows[IN_DIM + i0.y];
        a1.z = rows[IN_DIM + i0.z]; a1.w = rows[IN_DIM + i0.w];
        b1.x = rows[IN_DIM + i1.x]; b1.y = rows[IN_DIM + i1.y];
        b1.z = rows[IN_DIM + i1.z]; b1.w = rows[IN_DIM + i1.w];

        const v4f r0v = c0v + c1v * a0 + c2v * b0 + c3v * (a0 * b0);
        const v4f r1v = c0v + c1v * a1 + c2v * b1 + c3v * (a1 * b1);
        __builtin_nontemporal_store(r0v, (v4f*)(o0 + j));
        __builtin_nontemporal_store(r1v, (v4f*)(o1 + j));
    }
}

extern "C" void kernel_launch(void* const* d_in, const int* in_sizes, int n_in,
                              void* d_out, int out_size, void* d_ws, size_t ws_size,
                              hipStream_t stream) {
    const float* x = (const float*)d_in[0];
    const float* weights = (const float*)d_in[1];
    const int* idx0 = (const int*)d_in[2];
    const int* idx1 = (const int*)d_in[3];
    float* out = (float*)d_out;
    float* cp = (float*)d_ws;  // 4 planes x OUT_DIM floats = 128 KB scratch

    compute_c_kernel<<<OUT_DIM / 256, 256, 0, stream>>>(weights, cp);
    gate_kernel<<<NROWS / RPB, THREADS, 0, stream>>>(x, cp, idx0, idx1, out);
}